// Round 12
// baseline (367.953 us; speedup 1.0000x reference)
//
#include <hip/hip_runtime.h>
#include <hip/hip_bf16.h>
#include <stdint.h>

#define B_  4
#define S_  2048
#define D_  1024
#define H_  16
#define HD_ 64

typedef __attribute__((ext_vector_type(4))) float f32x4;
typedef __attribute__((ext_vector_type(8))) short bf16x8;

typedef const unsigned int __attribute__((address_space(1)))* gas_ptr;
typedef unsigned int __attribute__((address_space(3)))* las_ptr;

__device__ __forceinline__ void async16(const void* g, void* l) {
  __builtin_amdgcn_global_load_lds((gas_ptr)g, (las_ptr)l, 16, 0, 0);
}

// ---------------------------------------------------------------------------
// x fp32 -> bf16
// ---------------------------------------------------------------------------
__global__ __launch_bounds__(256) void cvt_x(const float* __restrict__ in,
                                             __hip_bfloat16* __restrict__ out,
                                             int n) {
  const int i = (blockIdx.x * blockDim.x + threadIdx.x) * 4;
  if (i >= n) return;
  const float4 v = *(const float4*)(in + i);
  union { ushort4 u; __hip_bfloat16 h[4]; } o;
  o.h[0] = (__hip_bfloat16)v.x;
  o.h[1] = (__hip_bfloat16)v.y;
  o.h[2] = (__hip_bfloat16)v.z;
  o.h[3] = (__hip_bfloat16)v.w;
  *(ushort4*)(out + i) = o.u;
}

// ---------------------------------------------------------------------------
// mask int32 -> expanded bf16-AND masks, WAVE-COALESCED layout.
// ---------------------------------------------------------------------------
__global__ __launch_bounds__(256) void expand_mask(const int* __restrict__ mk,
                                                   uint2* __restrict__ xm) {
  const unsigned j = blockIdx.x * 256 + threadIdx.x;
  const int mt = j & 3, lane = (j >> 2) & 63, kt = (j >> 8) & 31;
  const int qg = j >> 13;
  const int quad = lane >> 4, l16 = lane & 15;
  const size_t row = (size_t)qg * 16 + l16;     // = b*2048 + q
  const int key = kt * 64 + mt * 16 + quad * 4;
  const int4 m = *(const int4*)(mk + row * 2048 + key);
  uint2 o;
  o.x = (m.x ? 0xFFFFu : 0u) | (m.y ? 0xFFFF0000u : 0u);
  o.y = (m.z ? 0xFFFFu : 0u) | (m.w ? 0xFFFF0000u : 0u);
  xm[j] = o;
}

// ---------------------------------------------------------------------------
// weights fp32 [K,N] -> bf16 transposed [N,K]
// ---------------------------------------------------------------------------
__global__ void transpose_w(const float* __restrict__ Wq,
                            const float* __restrict__ Wk,
                            const float* __restrict__ Wv,
                            const float* __restrict__ Wo,
                            __hip_bfloat16* __restrict__ Wt_qkv,
                            __hip_bfloat16* __restrict__ Wt_o) {
  __shared__ float t[32][33];
  const int z = blockIdx.z;
  const float* W = (z == 0) ? Wq : (z == 1) ? Wk : (z == 2) ? Wv : Wo;
  __hip_bfloat16* Wt = (z < 3) ? (Wt_qkv + (size_t)z * D_ * D_) : Wt_o;
  const int x = blockIdx.x * 32 + threadIdx.x;
  const int y = blockIdx.y * 32 + threadIdx.y;
  t[threadIdx.y][threadIdx.x] = W[(size_t)y * D_ + x];
  __syncthreads();
  const int xo = blockIdx.y * 32 + threadIdx.x;
  const int yo = blockIdx.x * 32 + threadIdx.y;
  Wt[(size_t)yo * D_ + xo] = (__hip_bfloat16)t[threadIdx.x][threadIdx.y];
}

// ---------------------------------------------------------------------------
// QKV GEMM v2: 256x256 tile, 512 threads (8 waves = 4M x 2N), BK=64,
// 8-phase counted-vmcnt schedule (T3+T4+T5; m201 template adapted).
//
// Geometry: wave out 64x128 (acc[4][8]); per phase one quadrant
// (2 mt x 4 nt x 2 kc = 16 MFMA). LDS 128KB: sA[2][256x64] + sB[2][256x64].
// Staging unit = 2 async16 of 64 contiguous rows:
//   A-u0 rows 0-127, A-u1 128-255; B-u0 rows {0-63,128-191} (nh0 rows of
//   both wn groups), B-u1 {64-127,192-255}.
// Phase slots (iter i, tiles u=2i,u+1; u+1->buf1, u+2->buf0, u+3->buf1):
//   ph1:u1.B1  ph2:u1.A0  ph3:u1.A1  ph4:u2.B0  ph5:u2.B1  ph6:u2.A0
//   ph7:u2.A1  ph8:u3.B0
// W-A-R: each unit's overwrite is >=1 barrier after its region's last
// ds_read (checked per phase). Waits: vmcnt(2) at end-ph4 (tile u+1 landed,
// u2.B0 may fly) and end-ph8 (tile u+2 landed, u3.B0 may fly) — FIFO
// accounting: exactly 1 unit (2 loads) newer than the needed tile.
// Tail (it=7): ph4-8 staging skipped; end-ph4 waits vmcnt(0).
// Rule 18: sched_barrier(0) after every inline waitcnt.
// ---------------------------------------------------------------------------
__device__ __forceinline__ f32x4 mfma16(bf16x8 a, bf16x8 b, f32x4 c) {
  return __builtin_amdgcn_mfma_f32_16x16x32_bf16(a, b, c, 0, 0, 0);
}

template<int MH>
__device__ __forceinline__ void rdA(const char* base, int koff, bf16x8 (&af)[2][2]) {
#pragma unroll
  for (int m = 0; m < 2; ++m)
#pragma unroll
    for (int kc = 0; kc < 2; ++kc)
      af[m][kc] = *(const bf16x8*)(base + (MH * 2 + m) * 2048 + (koff ^ (kc * 64)));
}

template<int NH>
__device__ __forceinline__ void rdB(const char* base, int koff, bf16x8 (&bf)[4][2]) {
#pragma unroll
  for (int n = 0; n < 4; ++n)
#pragma unroll
    for (int kc = 0; kc < 2; ++kc)
      bf[n][kc] = *(const bf16x8*)(base + (NH * 4 + n) * 2048 + (koff ^ (kc * 64)));
}

template<int MH, int NH>
__device__ __forceinline__ void mm16(const bf16x8 (&af)[2][2], const bf16x8 (&bf)[4][2],
                                     f32x4 (&acc)[4][8]) {
  __builtin_amdgcn_s_setprio(1);
#pragma unroll
  for (int m = 0; m < 2; ++m)
#pragma unroll
    for (int n = 0; n < 4; ++n)
#pragma unroll
      for (int kc = 0; kc < 2; ++kc)
        acc[MH * 2 + m][NH * 4 + n] =
            mfma16(af[m][kc], bf[n][kc], acc[MH * 2 + m][NH * 4 + n]);
  __builtin_amdgcn_s_setprio(0);
}

__global__ __launch_bounds__(512, 2) void gemm_qkv(
    const __hip_bfloat16* __restrict__ A,
    const __hip_bfloat16* __restrict__ Bt,
    const float* __restrict__ bq,
    const float* __restrict__ bk,
    const float* __restrict__ bv,
    __hip_bfloat16* __restrict__ QKo,
    __hip_bfloat16* __restrict__ Vt) {
  __shared__ __hip_bfloat16 sA[2][256 * 64];
  __shared__ __hip_bfloat16 sB[2][256 * 64];
  const int t512 = threadIdx.x;
  const int wave = t512 >> 6, lane = t512 & 63, quad = lane >> 4, l16 = lane & 15;
  // XCD swizzle: nwg = 32*12 = 384, chunk 48/XCD
  const int wg  = blockIdx.x;
  const int swz = (wg & 7) * 48 + (wg >> 3);
  const int bm = (swz / 12) * 256;
  const int bn = (swz % 12) * 256;
  const int wm = (wave >> 1) * 64;    // 4 M-groups
  const int wn = (wave & 1) * 128;    // 2 N-groups

  // staging: instr covers 64 rows; thread t -> row r0+(t>>3), phys chunk t&7
  // sourcing logical chunk (t&7)^((t>>3)&7). LDS dest wave-uniform base.
  const int schk = (t512 & 7) ^ ((t512 >> 3) & 7);
  const __hip_bfloat16* gA = A  + ((size_t)bm + (t512 >> 3)) * 1024 + schk * 8;
  const __hip_bfloat16* gB = Bt + ((size_t)bn + (t512 >> 3)) * 1024 + schk * 8;
  char* const lA[2] = {(char*)&sA[0][0] + wave * 1024, (char*)&sA[1][0] + wave * 1024};
  char* const lB[2] = {(char*)&sB[0][0] + wave * 1024, (char*)&sB[1][0] + wave * 1024};

#define STG(GP, LP, R0, KT) \
  async16(GP + (size_t)(R0) * 1024 + (KT) * 64, LP + (R0) * 128)
#define UA0(bf_, kt_) { STG(gA, lA[bf_], 0,   kt_); STG(gA, lA[bf_], 64,  kt_); }
#define UA1(bf_, kt_) { STG(gA, lA[bf_], 128, kt_); STG(gA, lA[bf_], 192, kt_); }
#define UB0(bf_, kt_) { STG(gB, lB[bf_], 0,   kt_); STG(gB, lB[bf_], 128, kt_); }
#define UB1(bf_, kt_) { STG(gB, lB[bf_], 64,  kt_); STG(gB, lB[bf_], 192, kt_); }
#define BAR  __builtin_amdgcn_s_barrier()
#define LGKM0 { asm volatile("s_waitcnt lgkmcnt(0)" ::: "memory"); \
                __builtin_amdgcn_sched_barrier(0); }

  // fragment-read bases (row stride 128B; XOR chunk swizzle, proven 0-conflict)
  const int xl = l16 & 7;
  const int koff = (quad ^ xl) * 16;
  const char* rA[2] = {(char*)&sA[0][0] + (wm + l16) * 128,
                       (char*)&sA[1][0] + (wm + l16) * 128};
  const char* rB[2] = {(char*)&sB[0][0] + (wn + l16) * 128,
                       (char*)&sB[1][0] + (wn + l16) * 128};

  bf16x8 af[2][2], bfr[4][2];
  f32x4 acc[4][8] = {};

  // prologue: tile0 (buf0) full + tile1.B0 (buf1); t0's 8 loads oldest.
  UB0(0, 0); UB1(0, 0); UA0(0, 0); UA1(0, 0);
  UB0(1, 1);
  asm volatile("s_waitcnt vmcnt(2)" ::: "memory");
  __builtin_amdgcn_sched_barrier(0);
  BAR;
  __builtin_amdgcn_sched_barrier(0);

#pragma unroll 1
  for (int it = 0; it < 8; ++it) {
    const int k1 = 2 * it + 1, k2 = 2 * it + 2, k3 = 2 * it + 3;
    const bool st = (it < 7);
    // ---- tile u (buf0) ----
    // ph1 (mh0, nh0)
    rdB<0>(rB[0], koff, bfr); rdA<0>(rA[0], koff, af);
    UB1(1, k1);
    BAR; LGKM0; mm16<0, 0>(af, bfr, acc); BAR;
    // ph2 (mh1, nh0)
    rdA<1>(rA[0], koff, af);
    UA0(1, k1);
    BAR; LGKM0; mm16<1, 0>(af, bfr, acc); BAR;
    // ph3 (mh1, nh1)
    rdB<1>(rB[0], koff, bfr);
    UA1(1, k1);
    BAR; LGKM0; mm16<1, 1>(af, bfr, acc); BAR;
    // ph4 (mh0, nh1) + tile-boundary wait (tile u+1 must be landed)
    rdA<0>(rA[0], koff, af);
    if (st) UB0(0, k2);
    BAR; LGKM0; mm16<0, 1>(af, bfr, acc);
    if (st) { asm volatile("s_waitcnt vmcnt(2)" ::: "memory"); }
    else    { asm volatile("s_waitcnt vmcnt(0)" ::: "memory"); }
    __builtin_amdgcn_sched_barrier(0);
    BAR;
    __builtin_amdgcn_sched_barrier(0);
    // ---- tile u+1 (buf1) ----
    // ph5 (mh0, nh0)
    rdB<0>(rB[1], koff, bfr); rdA<0>(rA[1], koff, af);
    if (st) UB1(0, k2);
    BAR; LGKM0; mm16<0, 0>(af, bfr, acc); BAR;
    // ph6 (mh1, nh0)
    rdA<1>(rA[1], koff, af);
    if (st) UA0(0, k2);
    BAR; LGKM0; mm16<1, 0>(af, bfr, acc); BAR;
    // ph7 (mh1, nh1)
    rdB<1>(rB[1], koff, bfr);
    if (st) UA1(0, k2);
    BAR; LGKM0; mm16<1, 1>(af, bfr, acc); BAR;
    // ph8 (mh0, nh1) + tile-boundary wait (tile u+2 must be landed)
    rdA<0>(rA[1], koff, af);
    if (st) UB0(1, k3);
    BAR; LGKM0; mm16<0, 1>(af, bfr, acc);
    if (st) { asm volatile("s_waitcnt vmcnt(2)" ::: "memory"); }
    __builtin_amdgcn_sched_barrier(0);
    BAR;
    __builtin_amdgcn_sched_barrier(0);
  }

  // epilogue: row = bm+wm+mt*16+quad*4+r, col = bn+wn+nt*16+l16
#pragma unroll
  for (int mt = 0; mt < 4; ++mt) {
    const int row = bm + wm + mt * 16 + quad * 4;
#pragma unroll
    for (int nt = 0; nt < 8; ++nt) {
      const int col = bn + wn + nt * 16 + l16;
      f32x4 v = acc[mt][nt];
      if (col < 2048) {
        const float bias = (col < 1024) ? bq[col] : bk[col - 1024];
        const float sc = (col < 1024) ? 0.18033688011f : 1.0f;  // 0.125*log2(e)
#pragma unroll
        for (int r = 0; r < 4; ++r)
          QKo[(size_t)(row + r) * 2048 + col] = (__hip_bfloat16)((v[r] + bias) * sc);
      } else {
        const int cv = col - 2048;
        const float bias = bv[cv];
        const int hh = cv >> 6, d = cv & 63;
        const int bb = row >> 11, s0 = row & 2047;
        union { __hip_bfloat16 h[4]; unsigned long long u; } pk;
#pragma unroll
        for (int r = 0; r < 4; ++r) pk.h[r] = (__hip_bfloat16)(v[r] + bias);
        *(unsigned long long*)(Vt + ((size_t)(bb * 16 + hh) * 64 + d) * 2048 + s0) = pk.u;
      }
    }
  }
#undef STG
#undef UA0
#undef UA1
#undef UB0
#undef UB1
#undef BAR
#undef LGKM0
}

// ---------------------------------------------------------------------------
// Out-proj GEMM, BK=64 swizzled 128² (unchanged), fp32 output. XCD swizzle.
// ---------------------------------------------------------------------------
__global__ __launch_bounds__(256) void gemm_out(
    const __hip_bfloat16* __restrict__ A,
    const __hip_bfloat16* __restrict__ Bt,
    const float* __restrict__ b0,
    float* __restrict__ C,
    int N, int K) {
  __shared__ __hip_bfloat16 sA[128 * 64];
  __shared__ __hip_bfloat16 sB[128 * 64];
  const int tid  = threadIdx.x;
  const int wave = tid >> 6;
  const int lane = tid & 63;
  const int quad = lane >> 4;
  const int l16  = lane & 15;
  const int wg  = blockIdx.x;
  const int swz = (wg & 7) * 64 + (wg >> 3);
  const int bm = (swz >> 3) * 128;
  const int bn = (swz & 7) * 128;
  const int wm = (wave >> 1) * 64;
  const int wn = (wave & 1) * 64;

  const int srow = lane >> 3;
  const int schk = (lane & 7) ^ srow;
  const __hip_bfloat16* gA = A  + (size_t)(bm + wave * 32 + srow) * K + schk * 8;
  const __hip_bfloat16* gB = Bt + (size_t)(bn + wave * 32 + srow) * K + schk * 8;
  char* const lA = (char*)sA + wave * 32 * 128;
  char* const lB = (char*)sB + wave * 32 * 128;

  const int xl = l16 & 7;
  const int koff = (quad ^ xl) * 16;
  const char* pa = (const char*)sA + (wm + l16) * 128;
  const char* pb = (const char*)sB + (wn + l16) * 128;

  f32x4 acc[4][4] = {};

  for (int k0 = 0; k0 < K; k0 += 64) {
#pragma unroll
    for (int t = 0; t < 4; ++t) {
      async16(gA + (size_t)(t * 8) * K + k0, lA + t * 1024);
      async16(gB + (size_t)(t * 8) * K + k0, lB + t * 1024);
    }
    __syncthreads();
#pragma unroll
    for (int c = 0; c < 2; ++c) {
      const int off = koff ^ (c * 64);
      bf16x8 af[4], bf[4];
#pragma unroll
      for (int mt = 0; mt < 4; ++mt) af[mt] = *(const bf16x8*)(pa + mt * 2048 + off);
#pragma unroll
      for (int nt = 0; nt < 4; ++nt) bf[nt] = *(const bf16x8*)(pb + nt * 2048 + off);
#pragma unroll
      for (int mt = 0; mt < 4; ++mt)
#pragma unroll
        for (int nt = 0; nt < 4; ++nt)
          acc[mt][nt] = __builtin_amdgcn_mfma_f32_16x16x32_bf16(af[mt], bf[nt], acc[mt][nt], 0, 0, 0);
    }
    __syncthreads();
  }

#pragma unroll
  for (int mt = 0; mt < 4; ++mt) {
    const int row = bm + wm + mt * 16 + quad * 4;
#pragma unroll
    for (int nt = 0; nt < 4; ++nt) {
      const int col = bn + wn + nt * 16 + l16;
      const float bias = b0[col];
      f32x4 v = acc[mt][nt];
#pragma unroll
      for (int r = 0; r < 4; ++r)
        C[(size_t)(row + r) * N + col] = v[r] + bias;
    }
  }
}

// ---------------------------------------------------------------------------
// Flash attention v15 (unchanged; 103us, accepted near-floor for this
// structure). launch_bounds (256,4) — r9 showed 5 blocks/CU spills.
// ---------------------------------------------------------------------------
__global__ __launch_bounds__(256, 4) void flash_attn(
    const __hip_bfloat16* __restrict__ QK,            // [8192][2048]
    const __hip_bfloat16* __restrict__ Vt,            // [B*H*64][2048]
    const uint4* __restrict__ XM,                     // expanded masks
    __hip_bfloat16* __restrict__ O) {                 // [8192][1024]
  __shared__ __hip_bfloat16 sK[2][64 * 64];
  __shared__ __hip_bfloat16 sV[2][64 * 64];

  const int qt = blockIdx.x, h = blockIdx.y, b = blockIdx.z;
  const int tid = threadIdx.x;
  const int wave = tid >> 6, lane = tid & 63, quad = lane >> 4, l16 = lane & 15;
  const int qbase = qt * 128;
  const size_t brow = (size_t)b * S_;
  const int bh = b * H_ + h;

  // Q fragments direct from global: B-operand, lane n = l16 = q row.
  bf16x8 qf[2][2];
#pragma unroll
  for (int g = 0; g < 2; ++g) {
    const __hip_bfloat16* qrow =
        QK + (brow + qbase + g * 64 + wave * 16 + l16) * 2048 + h * 64;
#pragma unroll
    for (int c = 0; c < 2; ++c)
      qf[g][c] = *(const bf16x8*)(qrow + c * 32 + quad * 8);
  }

  // DMA staging: lane i of instr t covers row wave*16 + t*8 + (i>>3),
  // physical chunk i&7 = logical chunk (i&7)^(i>>3) (XOR swizzle).
  const int srow = lane >> 3;
  const int schk = (lane & 7) ^ srow;
  const __hip_bfloat16* gk0 =
      QK + (brow + wave * 16 + srow) * 2048 + 1024 + h * 64 + schk * 8;
  const __hip_bfloat16* gk1 = gk0 + (size_t)8 * 2048;
  const __hip_bfloat16* gv0 =
      Vt + ((size_t)bh * 64 + wave * 16 + srow) * 2048 + schk * 8;
  const __hip_bfloat16* gv1 = gv0 + (size_t)8 * 2048;
  char* const lK[2] = {(char*)&sK[0][0] + wave * 2048, (char*)&sK[1][0] + wave * 2048};
  char* const lV[2] = {(char*)&sV[0][0] + wave * 2048, (char*)&sV[1][0] + wave * 2048};

  // coalesced mask pointers: qg = b*128 + qt*8 + g*4 + wave; per (qg,kt)
  // a 128-uint4 (2KB) block; lane's slice = 2 uint4 at lane*2.
  const uint4* xpa =
      XM + ((size_t)(b * 128 + qt * 8 + wave) * 32) * 128 + (size_t)lane * 2;
  const uint4* xpb = xpa + (size_t)4 * 32 * 128;

  // fragment-read swizzle offsets (chunk c*4+quad, row parity l16&7)
  const int xl = l16 & 7;
  const int koff0 = ((quad ^ xl) * 16);        // c=0 chunk; c=1 = koff0^64
  const int rowb = l16 * 128;

  const bf16x8 onesv = {(short)0x3F80, (short)0x3F80, (short)0x3F80, (short)0x3F80,
                        (short)0x3F80, (short)0x3F80, (short)0x3F80, (short)0x3F80};
  f32x4 lacc[2] = {};
  f32x4 oacc[2][4] = {};

  // prologue: stage tile 0
  async16(gk0, lK[0]);
  async16(gk1, lK[0] + 1024);
  async16(gv0, lV[0]);
  async16(gv1, lV[0] + 1024);
  gk0 += (size_t)64 * 2048; gk1 += (size_t)64 * 2048;
  gv0 += 64; gv1 += 64;
  __syncthreads();

  const int NT = S_ / 64;
  for (int kt = 0; kt < NT; ++kt) {
    const int cur = kt & 1, nxt = cur ^ 1;

    // issue next tile's DMA (overlaps this tile's compute; disjoint buffer)
    if (kt + 1 < NT) {
      async16(gk0, lK[nxt]);
      async16(gk1, lK[nxt] + 1024);
      async16(gv0, lV[nxt]);
      async16(gv1, lV[nxt] + 1024);
      gk0 += (size_t)64 * 2048; gk1 += (size_t)64 * 2048;
      gv0 += 64; gv1 += 64;
    }
    // masks for THIS tile: direct loads (contiguous, L2-hot); independent
    // of everything above -> scheduler issues them before the MFMA cluster.
    const uint4 ca0 = xpa[(size_t)kt * 128];
    const uint4 ca1 = xpa[(size_t)kt * 128 + 1];
    const uint4 cb0 = xpb[(size_t)kt * 128];
    const uint4 cb1 = xpb[(size_t)kt * 128 + 1];

    // QK with fused exp/pack/AND-mask: kf read once feeds both q-groups.
    const char* bK = (const char*)&sK[cur][0] + rowb;
    unsigned pl[2][4][2];
    __builtin_amdgcn_s_setprio(1);
#pragma unroll
    for (int mt = 0; mt < 4; ++mt) {
      const bf16x8 kf0 = *(const bf16x8*)(bK + mt * 2048 + koff0);
      const bf16x8 kf1 = *(const bf16x8*)(bK + mt * 2048 + (koff0 ^ 64));
      f32x4 a0 = {}, a1 = {};
      a0 = __builtin_amdgcn_mfma_f32_16x16x32_bf16(kf0, qf[0][0], a0, 0, 0, 0);
      a0 = __builtin_amdgcn_mfma_f32_16x16x32_bf16(kf1, qf[0][1], a0, 0, 0, 0);
      a1 = __builtin_amdgcn_mfma_f32_16x16x32_bf16(kf0, qf[1][0], a1, 0, 0, 0);
      a1 = __builtin_amdgcn_mfma_f32_16x16x32_bf16(kf1, qf[1][1], a1, 0, 0, 0);
#pragma unroll
      for (int g = 0; g < 2; ++g) {
        const uint4 cc = g ? ((mt < 2) ? cb0 : cb1) : ((mt < 2) ? ca0 : ca1);
        const unsigned w0 = (mt & 1) ? cc.z : cc.x;
        const unsigned w1 = (mt & 1) ? cc.w : cc.y;
        const f32x4 av = g ? a1 : a0;
        union { __hip_bfloat16 h[2]; unsigned u; } c0, c1;
        c0.h[0] = (__hip_bfloat16)__builtin_amdgcn_exp2f(av[0]);
        c0.h[1] = (__hip_bfloat16)__builtin_amdgcn_exp2f(av[1]);
        c1.h[0] = (__hip_bfloat16)__builtin_amdgcn_exp2f(av[2]);
        c1.h[1] = (__hip_bfloat16)__builtin_amdgcn_exp2f(av[3]);
        pl[g][mt][0] = c0.u & w0;
        pl[g][mt][1] = c1.u & w1;
      }
    }
    __builtin_amdgcn_s_setprio(0);

    // In-register P^T -> B-operand redistribution (permlane swaps).
    bf16x8 pf[2][2];
#pragma unroll
    for (int g = 0; g < 2; ++g)
#pragma unroll
      for (int c = 0; c < 2; ++c) {
        unsigned e0 = pl[g][2 * c][0], o0 = pl[g][2 * c + 1][0];
        unsigned e1 = pl[g][2 * c][1], o1 = pl[g][2 * c + 1][1];
        asm("v_permlane32_swap_b32 %0, %1" : "+v"(e0), "+v"(o0));
        asm("v_permlane16_swap_b32 %0, %1" : "+v"(e0), "+v"(o0));
        asm("v_permlane32_swap_b32 %0, %1" : "+v"(e1), "+v"(o1));
        asm("v_permlane16_swap_b32 %0, %1" : "+v"(e1), "+v"(o1));
        union { unsigned u[4]; bf16x8 v; } uu;
        uu.u[0] = e0; uu.u[1] = e1; uu.u[2] = o0; uu.u[3] = o1;
        pf[g][c] = uu.v;
      }

    // PV: O^T += V^T · P^T ; vf read once, feeds both groups.
    const char* bV = (const char*)&sV[cur][0] + rowb;
    __builtin_amdgcn_s_setprio(1);
#pragma unroll
    for (int ht = 0; ht < 4; ++ht) {
      const bf16x8 vf0 = *(const bf16x8*)(bV + ht * 2048 + koff0);
      const bf16x8 vf1 = *(const bf16x8*)(bV + ht * 2048 + (koff0 ^ 64));
      oacc[0][ht] = __builtin_amdgcn_mfma_f32_16x16x32_bf16(vf0, pf[0][0], oacc[0][ht], 0, 0, 0);
      oacc[0][ht] = __builtin_amdgcn_mfma_f32_16x16x32_bf16(vf1, pf[0][1], oacc[0][ht], 0, 0, 0);
      oacc[1][ht] = __builtin_amdgcn_mfma_f32_16x16x32_bf16(vf0, pf[1][0], oacc[1][ht], 0, 0, 0);
      oacc[1][ht] = __builtin_amdgcn_mfma_f32_16x16x32_bf16(vf1, pf[1][1], oacc[1][ht], 0, 0, 0);
    }
    // l row-sums via ones-MFMA: D[r][q] = sum_k P[k][q] for every r.
    lacc[0] = __builtin_amdgcn_mfma_f32_16x16x32_bf16(onesv, pf[0][0], lacc[0], 0, 0, 0);
    lacc[0] = __builtin_amdgcn_mfma_f32_16x16x32_bf16(onesv, pf[0][1], lacc[0], 0, 0, 0);
    lacc[1] = __builtin_amdgcn_mfma_f32_16x16x32_bf16(onesv, pf[1][0], lacc[1], 0, 0, 0);
    lacc[1] = __builtin_amdgcn_mfma_f32_16x16x32_bf16(onesv, pf[1][1], lacc[1], 0, 0, 0);
    __builtin_amdgcn_s_setprio(0);

    __syncthreads();  // drains DMA (vmcnt) + LDS ops before buffer swap
  }

  // epilogue: every lane holds its q-column's sum in lacc[g][*]
#pragma unroll
  for (int g = 0; g < 2; ++g) {
    const float l = lacc[g][0];
    const float inv = (l > 0.f) ? 1.f / l : 0.f;
    __hip_bfloat16* orow =
        O + (brow + qbase + g * 64 + wave * 16 + l16) * 1024 + h * 64;
#pragma unroll
    for (int ht = 0; ht < 4; ++ht) {
      union { __hip_bfloat16 h[4]; unsigned long long u; } ok_;
#pragma unroll
      for (int r = 0; r < 4; ++r) ok_.h[r] = (__hip_bfloat16)(oacc[g][ht][r] * inv);
      *(unsigned long long*)(orow + ht * 16 + quad * 4) = ok_.u;
    }
  }
}

// ---------------------------------------------------------------------------
extern "C" void kernel_launch(void* const* d_in, const int* in_sizes, int n_in,
                              void* d_out, int out_size, void* d_ws, size_t ws_size,
                              hipStream_t stream) {
  const float* x  = (const float*)d_in[0];
  const int*   mk = (const int*)d_in[1];
  const float* Wq = (const float*)d_in[2];
  const float* bq = (const float*)d_in[3];
  const float* Wk = (const float*)d_in[4];
  const float* bk = (const float*)d_in[5];
  const float* Wv = (const float*)d_in[6];
  const float* bv = (const float*)d_in[7];
  const float* Wo = (const float*)d_in[8];
  const float* bo = (const float*)d_in[9];
  float* out = (float*)d_out;

  __hip_bfloat16* X16    = (__hip_bfloat16*)d_ws;                  // [8192][1024]
  __hip_bfloat16* Wt_qkv = X16 + (size_t)B_ * S_ * D_;             // [3072][1024]
  __hip_bfloat16* Wt_o   = Wt_qkv + (size_t)3 * D_ * D_;           // [1024][1024]
  __hip_bfloat16* QK     = Wt_o + (size_t)D_ * D_;                 // [8192][2048]
  __hip_bfloat16* Vt     = QK + (size_t)B_ * S_ * 2 * D_;          // [4096][2048]
  __hip_bfloat16* Obuf   = Vt + (size_t)B_ * H_ * HD_ * S_;        // [8192][1024]
  unsigned* xmask = (unsigned*)(Obuf + (size_t)B_ * S_ * D_);      // 33.5 MB

  const int nx = B_ * S_ * D_;
  cvt_x<<<dim3((nx / 4 + 255) / 256), 256, 0, stream>>>(x, X16, nx);
  transpose_w<<<dim3(32, 32, 4), dim3(32, 32), 0, stream>>>(Wq, Wk, Wv, Wo, Wt_qkv, Wt_o);
  expand_mask<<<dim3((int)((size_t)B_ * S_ * S_ / 4 / 256)), 256, 0, stream>>>(
      mk, (uint2*)xmask);
  gemm_qkv<<<dim3(384), 512, 0, stream>>>(
      X16, Wt_qkv, bq, bk, bv, QK, Vt);
  flash_attn<<<dim3(S_ / 128, H_, B_), 256, 0, stream>>>(
      QK, Vt, (const uint4*)xmask, Obuf);
  gemm_out<<<dim3(8 * 64), 256, 0, stream>>>(
      Obuf, Wt_o, bo, out, D_, D_);
}

// Round 13
// 356.144 us; speedup vs baseline: 1.0332x; 1.0332x over previous
//
#include <hip/hip_runtime.h>
#include <hip/hip_bf16.h>
#include <stdint.h>

#define B_  4
#define S_  2048
#define D_  1024
#define H_  16
#define HD_ 64

typedef __attribute__((ext_vector_type(4))) float f32x4;
typedef __attribute__((ext_vector_type(8))) short bf16x8;

typedef const unsigned int __attribute__((address_space(1)))* gas_ptr;
typedef unsigned int __attribute__((address_space(3)))* las_ptr;

__device__ __forceinline__ void async16(const void* g, void* l) {
  __builtin_amdgcn_global_load_lds((gas_ptr)g, (las_ptr)l, 16, 0, 0);
}

// ---------------------------------------------------------------------------
// x fp32 -> bf16
// ---------------------------------------------------------------------------
__global__ __launch_bounds__(256) void cvt_x(const float* __restrict__ in,
                                             __hip_bfloat16* __restrict__ out,
                                             int n) {
  const int i = (blockIdx.x * blockDim.x + threadIdx.x) * 4;
  if (i >= n) return;
  const float4 v = *(const float4*)(in + i);
  union { ushort4 u; __hip_bfloat16 h[4]; } o;
  o.h[0] = (__hip_bfloat16)v.x;
  o.h[1] = (__hip_bfloat16)v.y;
  o.h[2] = (__hip_bfloat16)v.z;
  o.h[3] = (__hip_bfloat16)v.w;
  *(ushort4*)(out + i) = o.u;
}

// ---------------------------------------------------------------------------
// mask int32 -> expanded bf16-AND masks, WAVE-COALESCED layout.
// uint2 j decode: mt=j&3, lane=(j>>2)&63, kt=(j>>8)&31, qg=j>>13
// -> per (qg,kt) a 2KB contiguous block; flash lane reads its 32B slice.
// ---------------------------------------------------------------------------
__global__ __launch_bounds__(256) void expand_mask(const int* __restrict__ mk,
                                                   uint2* __restrict__ xm) {
  const unsigned j = blockIdx.x * 256 + threadIdx.x;
  const int mt = j & 3, lane = (j >> 2) & 63, kt = (j >> 8) & 31;
  const int qg = j >> 13;
  const int quad = lane >> 4, l16 = lane & 15;
  const size_t row = (size_t)qg * 16 + l16;     // = b*2048 + q
  const int key = kt * 64 + mt * 16 + quad * 4;
  const int4 m = *(const int4*)(mk + row * 2048 + key);
  uint2 o;
  o.x = (m.x ? 0xFFFFu : 0u) | (m.y ? 0xFFFF0000u : 0u);
  o.y = (m.z ? 0xFFFFu : 0u) | (m.w ? 0xFFFF0000u : 0u);
  xm[j] = o;
}

// ---------------------------------------------------------------------------
// weights fp32 [K,N] -> bf16 transposed [N,K]
// ---------------------------------------------------------------------------
__global__ void transpose_w(const float* __restrict__ Wq,
                            const float* __restrict__ Wk,
                            const float* __restrict__ Wv,
                            const float* __restrict__ Wo,
                            __hip_bfloat16* __restrict__ Wt_qkv,
                            __hip_bfloat16* __restrict__ Wt_o) {
  __shared__ float t[32][33];
  const int z = blockIdx.z;
  const float* W = (z == 0) ? Wq : (z == 1) ? Wk : (z == 2) ? Wv : Wo;
  __hip_bfloat16* Wt = (z < 3) ? (Wt_qkv + (size_t)z * D_ * D_) : Wt_o;
  const int x = blockIdx.x * 32 + threadIdx.x;
  const int y = blockIdx.y * 32 + threadIdx.y;
  t[threadIdx.y][threadIdx.x] = W[(size_t)y * D_ + x];
  __syncthreads();
  const int xo = blockIdx.y * 32 + threadIdx.x;
  const int yo = blockIdx.x * 32 + threadIdx.y;
  Wt[(size_t)yo * D_ + xo] = (__hip_bfloat16)t[threadIdx.x][threadIdx.y];
}

// ---------------------------------------------------------------------------
// QKV GEMM, BK=64 + XOR-swizzled LDS, 128² 2-phase (round-11 version,
// reverted from the 8-phase 256² port: that was correct but null-to-negative
// here — 384-block grid at 1 block/CU has a 75% dispatch-tail ceiling and
// the shallow 1-unit pipeline undercovers HBM latency at K=1024).
// XCD swizzle (T1): nwg=1536, chunk 192/XCD = 8 M-rows.
// ---------------------------------------------------------------------------
__global__ __launch_bounds__(256) void gemm_qkv(
    const __hip_bfloat16* __restrict__ A,
    const __hip_bfloat16* __restrict__ Bt,
    const float* __restrict__ bq,
    const float* __restrict__ bk,
    const float* __restrict__ bv,
    __hip_bfloat16* __restrict__ QKo,
    __hip_bfloat16* __restrict__ Vt) {
  __shared__ __hip_bfloat16 sA[128 * 64];
  __shared__ __hip_bfloat16 sB[128 * 64];
  const int K = 1024;
  const int tid  = threadIdx.x;
  const int wave = tid >> 6;
  const int lane = tid & 63;
  const int quad = lane >> 4;
  const int l16  = lane & 15;
  const int wg  = blockIdx.x;
  const int swz = (wg & 7) * 192 + (wg >> 3);
  const int bm = (swz / 24) * 128;
  const int bn = (swz % 24) * 128;
  const int wm = (wave >> 1) * 64;
  const int wn = (wave & 1) * 64;

  const int srow = lane >> 3;
  const int schk = (lane & 7) ^ srow;
  const __hip_bfloat16* gA = A  + (size_t)(bm + wave * 32 + srow) * K + schk * 8;
  const __hip_bfloat16* gB = Bt + (size_t)(bn + wave * 32 + srow) * K + schk * 8;
  char* const lA = (char*)sA + wave * 32 * 128;
  char* const lB = (char*)sB + wave * 32 * 128;

  const int xl = l16 & 7;
  const int koff = (quad ^ xl) * 16;
  const char* pa = (const char*)sA + (wm + l16) * 128;
  const char* pb = (const char*)sB + (wn + l16) * 128;

  f32x4 acc[4][4] = {};

  for (int k0 = 0; k0 < K; k0 += 64) {
#pragma unroll
    for (int t = 0; t < 4; ++t) {
      async16(gA + (size_t)(t * 8) * K + k0, lA + t * 1024);
      async16(gB + (size_t)(t * 8) * K + k0, lB + t * 1024);
    }
    __syncthreads();
#pragma unroll
    for (int c = 0; c < 2; ++c) {
      const int off = koff ^ (c * 64);
      bf16x8 af[4], bf[4];
#pragma unroll
      for (int mt = 0; mt < 4; ++mt) af[mt] = *(const bf16x8*)(pa + mt * 2048 + off);
#pragma unroll
      for (int nt = 0; nt < 4; ++nt) bf[nt] = *(const bf16x8*)(pb + nt * 2048 + off);
#pragma unroll
      for (int mt = 0; mt < 4; ++mt)
#pragma unroll
        for (int nt = 0; nt < 4; ++nt)
          acc[mt][nt] = __builtin_amdgcn_mfma_f32_16x16x32_bf16(af[mt], bf[nt], acc[mt][nt], 0, 0, 0);
    }
    __syncthreads();
  }

#pragma unroll
  for (int mt = 0; mt < 4; ++mt) {
    const int row = bm + wm + mt * 16 + quad * 4;
#pragma unroll
    for (int nt = 0; nt < 4; ++nt) {
      const int col = bn + wn + nt * 16 + l16;
      f32x4 v = acc[mt][nt];
      if (col < 2048) {
        const float bias = (col < 1024) ? bq[col] : bk[col - 1024];
        const float sc = (col < 1024) ? 0.18033688011f : 1.0f;  // 0.125*log2(e)
#pragma unroll
        for (int r = 0; r < 4; ++r)
          QKo[(size_t)(row + r) * 2048 + col] = (__hip_bfloat16)((v[r] + bias) * sc);
      } else {
        const int cv = col - 2048;
        const float bias = bv[cv];
        const int hh = cv >> 6, d = cv & 63;
        const int bb = row >> 11, s0 = row & 2047;
        union { __hip_bfloat16 h[4]; unsigned long long u; } pk;
#pragma unroll
        for (int r = 0; r < 4; ++r) pk.h[r] = (__hip_bfloat16)(v[r] + bias);
        *(unsigned long long*)(Vt + ((size_t)(bb * 16 + hh) * 64 + d) * 2048 + s0) = pk.u;
      }
    }
  }
}

// ---------------------------------------------------------------------------
// Out-proj GEMM, BK=64 swizzled, fp32 output. XCD swizzle.
// ---------------------------------------------------------------------------
__global__ __launch_bounds__(256) void gemm_out(
    const __hip_bfloat16* __restrict__ A,
    const __hip_bfloat16* __restrict__ Bt,
    const float* __restrict__ b0,
    float* __restrict__ C,
    int N, int K) {
  __shared__ __hip_bfloat16 sA[128 * 64];
  __shared__ __hip_bfloat16 sB[128 * 64];
  const int tid  = threadIdx.x;
  const int wave = tid >> 6;
  const int lane = tid & 63;
  const int quad = lane >> 4;
  const int l16  = lane & 15;
  const int wg  = blockIdx.x;
  const int swz = (wg & 7) * 64 + (wg >> 3);
  const int bm = (swz >> 3) * 128;
  const int bn = (swz & 7) * 128;
  const int wm = (wave >> 1) * 64;
  const int wn = (wave & 1) * 64;

  const int srow = lane >> 3;
  const int schk = (lane & 7) ^ srow;
  const __hip_bfloat16* gA = A  + (size_t)(bm + wave * 32 + srow) * K + schk * 8;
  const __hip_bfloat16* gB = Bt + (size_t)(bn + wave * 32 + srow) * K + schk * 8;
  char* const lA = (char*)sA + wave * 32 * 128;
  char* const lB = (char*)sB + wave * 32 * 128;

  const int xl = l16 & 7;
  const int koff = (quad ^ xl) * 16;
  const char* pa = (const char*)sA + (wm + l16) * 128;
  const char* pb = (const char*)sB + (wn + l16) * 128;

  f32x4 acc[4][4] = {};

  for (int k0 = 0; k0 < K; k0 += 64) {
#pragma unroll
    for (int t = 0; t < 4; ++t) {
      async16(gA + (size_t)(t * 8) * K + k0, lA + t * 1024);
      async16(gB + (size_t)(t * 8) * K + k0, lB + t * 1024);
    }
    __syncthreads();
#pragma unroll
    for (int c = 0; c < 2; ++c) {
      const int off = koff ^ (c * 64);
      bf16x8 af[4], bf[4];
#pragma unroll
      for (int mt = 0; mt < 4; ++mt) af[mt] = *(const bf16x8*)(pa + mt * 2048 + off);
#pragma unroll
      for (int nt = 0; nt < 4; ++nt) bf[nt] = *(const bf16x8*)(pb + nt * 2048 + off);
#pragma unroll
      for (int mt = 0; mt < 4; ++mt)
#pragma unroll
        for (int nt = 0; nt < 4; ++nt)
          acc[mt][nt] = __builtin_amdgcn_mfma_f32_16x16x32_bf16(af[mt], bf[nt], acc[mt][nt], 0, 0, 0);
    }
    __syncthreads();
  }

#pragma unroll
  for (int mt = 0; mt < 4; ++mt) {
    const int row = bm + wm + mt * 16 + quad * 4;
#pragma unroll
    for (int nt = 0; nt < 4; ++nt) {
      const int col = bn + wn + nt * 16 + l16;
      const float bias = b0[col];
      f32x4 v = acc[mt][nt];
#pragma unroll
      for (int r = 0; r < 4; ++r)
        C[(size_t)(row + r) * N + col] = v[r] + bias;
    }
  }
}

// ---------------------------------------------------------------------------
// Flash attention v15 (unchanged; 102-103us). launch_bounds (256,4) —
// r9 showed 5 blocks/CU caps VGPR at 48 and spills catastrophically.
// ---------------------------------------------------------------------------
__global__ __launch_bounds__(256, 4) void flash_attn(
    const __hip_bfloat16* __restrict__ QK,            // [8192][2048]
    const __hip_bfloat16* __restrict__ Vt,            // [B*H*64][2048]
    const uint4* __restrict__ XM,                     // expanded masks
    __hip_bfloat16* __restrict__ O) {                 // [8192][1024]
  __shared__ __hip_bfloat16 sK[2][64 * 64];
  __shared__ __hip_bfloat16 sV[2][64 * 64];

  const int qt = blockIdx.x, h = blockIdx.y, b = blockIdx.z;
  const int tid = threadIdx.x;
  const int wave = tid >> 6, lane = tid & 63, quad = lane >> 4, l16 = lane & 15;
  const int qbase = qt * 128;
  const size_t brow = (size_t)b * S_;
  const int bh = b * H_ + h;

  // Q fragments direct from global: B-operand, lane n = l16 = q row.
  bf16x8 qf[2][2];
#pragma unroll
  for (int g = 0; g < 2; ++g) {
    const __hip_bfloat16* qrow =
        QK + (brow + qbase + g * 64 + wave * 16 + l16) * 2048 + h * 64;
#pragma unroll
    for (int c = 0; c < 2; ++c)
      qf[g][c] = *(const bf16x8*)(qrow + c * 32 + quad * 8);
  }

  // DMA staging: lane i of instr t covers row wave*16 + t*8 + (i>>3),
  // physical chunk i&7 = logical chunk (i&7)^(i>>3) (XOR swizzle).
  const int srow = lane >> 3;
  const int schk = (lane & 7) ^ srow;
  const __hip_bfloat16* gk0 =
      QK + (brow + wave * 16 + srow) * 2048 + 1024 + h * 64 + schk * 8;
  const __hip_bfloat16* gk1 = gk0 + (size_t)8 * 2048;
  const __hip_bfloat16* gv0 =
      Vt + ((size_t)bh * 64 + wave * 16 + srow) * 2048 + schk * 8;
  const __hip_bfloat16* gv1 = gv0 + (size_t)8 * 2048;
  char* const lK[2] = {(char*)&sK[0][0] + wave * 2048, (char*)&sK[1][0] + wave * 2048};
  char* const lV[2] = {(char*)&sV[0][0] + wave * 2048, (char*)&sV[1][0] + wave * 2048};

  // coalesced mask pointers: qg = b*128 + qt*8 + g*4 + wave; per (qg,kt)
  // a 128-uint4 (2KB) block; lane's slice = 2 uint4 at lane*2.
  const uint4* xpa =
      XM + ((size_t)(b * 128 + qt * 8 + wave) * 32) * 128 + (size_t)lane * 2;
  const uint4* xpb = xpa + (size_t)4 * 32 * 128;

  // fragment-read swizzle offsets (chunk c*4+quad, row parity l16&7)
  const int xl = l16 & 7;
  const int koff0 = ((quad ^ xl) * 16);        // c=0 chunk; c=1 = koff0^64
  const int rowb = l16 * 128;

  const bf16x8 onesv = {(short)0x3F80, (short)0x3F80, (short)0x3F80, (short)0x3F80,
                        (short)0x3F80, (short)0x3F80, (short)0x3F80, (short)0x3F80};
  f32x4 lacc[2] = {};
  f32x4 oacc[2][4] = {};

  // prologue: stage tile 0
  async16(gk0, lK[0]);
  async16(gk1, lK[0] + 1024);
  async16(gv0, lV[0]);
  async16(gv1, lV[0] + 1024);
  gk0 += (size_t)64 * 2048; gk1 += (size_t)64 * 2048;
  gv0 += 64; gv1 += 64;
  __syncthreads();

  const int NT = S_ / 64;
  for (int kt = 0; kt < NT; ++kt) {
    const int cur = kt & 1, nxt = cur ^ 1;

    // issue next tile's DMA (overlaps this tile's compute; disjoint buffer)
    if (kt + 1 < NT) {
      async16(gk0, lK[nxt]);
      async16(gk1, lK[nxt] + 1024);
      async16(gv0, lV[nxt]);
      async16(gv1, lV[nxt] + 1024);
      gk0 += (size_t)64 * 2048; gk1 += (size_t)64 * 2048;
      gv0 += 64; gv1 += 64;
    }
    // masks for THIS tile: direct loads (contiguous, L2-hot); independent
    // of everything above -> scheduler issues them before the MFMA cluster.
    const uint4 ca0 = xpa[(size_t)kt * 128];
    const uint4 ca1 = xpa[(size_t)kt * 128 + 1];
    const uint4 cb0 = xpb[(size_t)kt * 128];
    const uint4 cb1 = xpb[(size_t)kt * 128 + 1];

    // QK with fused exp/pack/AND-mask: kf read once feeds both q-groups.
    const char* bK = (const char*)&sK[cur][0] + rowb;
    unsigned pl[2][4][2];
    __builtin_amdgcn_s_setprio(1);
#pragma unroll
    for (int mt = 0; mt < 4; ++mt) {
      const bf16x8 kf0 = *(const bf16x8*)(bK + mt * 2048 + koff0);
      const bf16x8 kf1 = *(const bf16x8*)(bK + mt * 2048 + (koff0 ^ 64));
      f32x4 a0 = {}, a1 = {};
      a0 = __builtin_amdgcn_mfma_f32_16x16x32_bf16(kf0, qf[0][0], a0, 0, 0, 0);
      a0 = __builtin_amdgcn_mfma_f32_16x16x32_bf16(kf1, qf[0][1], a0, 0, 0, 0);
      a1 = __builtin_amdgcn_mfma_f32_16x16x32_bf16(kf0, qf[1][0], a1, 0, 0, 0);
      a1 = __builtin_amdgcn_mfma_f32_16x16x32_bf16(kf1, qf[1][1], a1, 0, 0, 0);
#pragma unroll
      for (int g = 0; g < 2; ++g) {
        const uint4 cc = g ? ((mt < 2) ? cb0 : cb1) : ((mt < 2) ? ca0 : ca1);
        const unsigned w0 = (mt & 1) ? cc.z : cc.x;
        const unsigned w1 = (mt & 1) ? cc.w : cc.y;
        const f32x4 av = g ? a1 : a0;
        union { __hip_bfloat16 h[2]; unsigned u; } c0, c1;
        c0.h[0] = (__hip_bfloat16)__builtin_amdgcn_exp2f(av[0]);
        c0.h[1] = (__hip_bfloat16)__builtin_amdgcn_exp2f(av[1]);
        c1.h[0] = (__hip_bfloat16)__builtin_amdgcn_exp2f(av[2]);
        c1.h[1] = (__hip_bfloat16)__builtin_amdgcn_exp2f(av[3]);
        pl[g][mt][0] = c0.u & w0;
        pl[g][mt][1] = c1.u & w1;
      }
    }
    __builtin_amdgcn_s_setprio(0);

    // In-register P^T -> B-operand redistribution (permlane swaps).
    // VDST = even-mt word (E), SRC0 = odd-mt word (O); after the two swaps
    // E = pf words {0,1}, O = pf words {2,3}.
    bf16x8 pf[2][2];
#pragma unroll
    for (int g = 0; g < 2; ++g)
#pragma unroll
      for (int c = 0; c < 2; ++c) {
        unsigned e0 = pl[g][2 * c][0], o0 = pl[g][2 * c + 1][0];
        unsigned e1 = pl[g][2 * c][1], o1 = pl[g][2 * c + 1][1];
        asm("v_permlane32_swap_b32 %0, %1" : "+v"(e0), "+v"(o0));
        asm("v_permlane16_swap_b32 %0, %1" : "+v"(e0), "+v"(o0));
        asm("v_permlane32_swap_b32 %0, %1" : "+v"(e1), "+v"(o1));
        asm("v_permlane16_swap_b32 %0, %1" : "+v"(e1), "+v"(o1));
        union { unsigned u[4]; bf16x8 v; } uu;
        uu.u[0] = e0; uu.u[1] = e1; uu.u[2] = o0; uu.u[3] = o1;
        pf[g][c] = uu.v;
      }

    // PV: O^T += V^T · P^T ; vf read once, feeds both groups.
    const char* bV = (const char*)&sV[cur][0] + rowb;
    __builtin_amdgcn_s_setprio(1);
#pragma unroll
    for (int ht = 0; ht < 4; ++ht) {
      const bf16x8 vf0 = *(const bf16x8*)(bV + ht * 2048 + koff0);
      const bf16x8 vf1 = *(const bf16x8*)(bV + ht * 2048 + (koff0 ^ 64));
      oacc[0][ht] = __builtin_amdgcn_mfma_f32_16x16x32_bf16(vf0, pf[0][0], oacc[0][ht], 0, 0, 0);
      oacc[0][ht] = __builtin_amdgcn_mfma_f32_16x16x32_bf16(vf1, pf[0][1], oacc[0][ht], 0, 0, 0);
      oacc[1][ht] = __builtin_amdgcn_mfma_f32_16x16x32_bf16(vf0, pf[1][0], oacc[1][ht], 0, 0, 0);
      oacc[1][ht] = __builtin_amdgcn_mfma_f32_16x16x32_bf16(vf1, pf[1][1], oacc[1][ht], 0, 0, 0);
    }
    // l row-sums via ones-MFMA: D[r][q] = sum_k P[k][q] for every r.
    lacc[0] = __builtin_amdgcn_mfma_f32_16x16x32_bf16(onesv, pf[0][0], lacc[0], 0, 0, 0);
    lacc[0] = __builtin_amdgcn_mfma_f32_16x16x32_bf16(onesv, pf[0][1], lacc[0], 0, 0, 0);
    lacc[1] = __builtin_amdgcn_mfma_f32_16x16x32_bf16(onesv, pf[1][0], lacc[1], 0, 0, 0);
    lacc[1] = __builtin_amdgcn_mfma_f32_16x16x32_bf16(onesv, pf[1][1], lacc[1], 0, 0, 0);
    __builtin_amdgcn_s_setprio(0);

    __syncthreads();  // drains DMA (vmcnt) + LDS ops before buffer swap
  }

  // epilogue: every lane holds its q-column's sum in lacc[g][*]
#pragma unroll
  for (int g = 0; g < 2; ++g) {
    const float l = lacc[g][0];
    const float inv = (l > 0.f) ? 1.f / l : 0.f;
    __hip_bfloat16* orow =
        O + (brow + qbase + g * 64 + wave * 16 + l16) * 1024 + h * 64;
#pragma unroll
    for (int ht = 0; ht < 4; ++ht) {
      union { __hip_bfloat16 h[4]; unsigned long long u; } ok_;
#pragma unroll
      for (int r = 0; r < 4; ++r) ok_.h[r] = (__hip_bfloat16)(oacc[g][ht][r] * inv);
      *(unsigned long long*)(orow + ht * 16 + quad * 4) = ok_.u;
    }
  }
}

// ---------------------------------------------------------------------------
extern "C" void kernel_launch(void* const* d_in, const int* in_sizes, int n_in,
                              void* d_out, int out_size, void* d_ws, size_t ws_size,
                              hipStream_t stream) {
  const float* x  = (const float*)d_in[0];
  const int*   mk = (const int*)d_in[1];
  const float* Wq = (const float*)d_in[2];
  const float* bq = (const float*)d_in[3];
  const float* Wk = (const float*)d_in[4];
  const float* bk = (const float*)d_in[5];
  const float* Wv = (const float*)d_in[6];
  const float* bv = (const float*)d_in[7];
  const float* Wo = (const float*)d_in[8];
  const float* bo = (const float*)d_in[9];
  float* out = (float*)d_out;

  __hip_bfloat16* X16    = (__hip_bfloat16*)d_ws;                  // [8192][1024]
  __hip_bfloat16* Wt_qkv = X16 + (size_t)B_ * S_ * D_;             // [3072][1024]
  __hip_bfloat16* Wt_o   = Wt_qkv + (size_t)3 * D_ * D_;           // [1024][1024]
  __hip_bfloat16* QK     = Wt_o + (size_t)D_ * D_;                 // [8192][2048]
  __hip_bfloat16* Vt     = QK + (size_t)B_ * S_ * 2 * D_;          // [4096][2048]
  __hip_bfloat16* Obuf   = Vt + (size_t)B_ * H_ * HD_ * S_;        // [8192][1024]
  unsigned* xmask = (unsigned*)(Obuf + (size_t)B_ * S_ * D_);      // 33.5 MB

  const int nx = B_ * S_ * D_;
  cvt_x<<<dim3((nx / 4 + 255) / 256), 256, 0, stream>>>(x, X16, nx);
  transpose_w<<<dim3(32, 32, 4), dim3(32, 32), 0, stream>>>(Wq, Wk, Wv, Wo, Wt_qkv, Wt_o);
  expand_mask<<<dim3((int)((size_t)B_ * S_ * S_ / 4 / 256)), 256, 0, stream>>>(
      mk, (uint2*)xmask);
  gemm_qkv<<<dim3(24 * 64), 256, 0, stream>>>(
      X16, Wt_qkv, bq, bk, bv, QK, Vt);
  flash_attn<<<dim3(S_ / 128, H_, B_), 256, 0, stream>>>(
      QK, Vt, (const uint4*)xmask, Obuf);
  gemm_out<<<dim3(8 * 64), 256, 0, stream>>>(
      Obuf, Wt_o, bo, out, D_, D_);
}